// Round 1
// baseline (112.564 us; speedup 1.0000x reference)
//
#include <hip/hip_runtime.h>

// SbS hidden dynamics: per-pixel serial scan over T spikes.
// dims fixed by the problem:
#define BB      16
#define TT      128
#define XDIM    16
#define YDIM    16
#define IN_DIM  256
#define H_DIM   64

// Mapping: 1 wave (64 lanes) per pixel, lane = h index.
// Block = 256 threads = 4 waves = 4 pixels sharing (b, x), y in {y0..y0+3}.
// Grid = B * X * (Y/4) = 16*16*4 = 1024 blocks -> 4 blocks/CU, 4 waves/SIMD.

__global__ __launch_bounds__(256) void sbs_scan_kernel(
    const int*   __restrict__ spikes,   // [B,T,X,Y]
    const float* __restrict__ eps_xy,   // [IN,X,Y]
    const float* __restrict__ eps_t,    // [T]
    const float* __restrict__ weights,  // [IN,H]
    const float* __restrict__ h_init,   // [H]
    const float* __restrict__ fo_ptr,   // [1]
    float*       __restrict__ out)      // [B,H,X,Y]
{
    __shared__ float s_eps[IN_DIM][4];      // eps_xy[i, x, y0+yy]   4 KB
    __shared__ int   s_spk[4][TT];          // per-wave spike seq    2 KB
    __shared__ float s_et[TT];              // eps_t                 0.5 KB
    __shared__ float s_out[4][H_DIM + 1];   // output transpose      ~1 KB

    const int tid  = threadIdx.x;
    const int wave = tid >> 6;
    const int lane = tid & 63;

    const int bi = blockIdx.x;
    const int b  = bi >> 6;          // 16 b
    const int x  = (bi >> 2) & 15;   // 16 x
    const int y0 = (bi & 3) << 2;    // 4 y-groups
    const int y  = y0 + wave;

    // ---- stage eps_xy columns for the block's 4 y values (1024 floats) ----
    {
        int i  = tid;                 // 256 threads, 4 elems each
        #pragma unroll
        for (int k = 0; k < 4; ++k) {
            int ii = i >> 2, yy = i & 3;
            s_eps[ii][yy] = eps_xy[ii * (XDIM * YDIM) + x * YDIM + y0 + yy];
            i += 256;
        }
    }
    if (tid < TT) s_et[tid] = eps_t[tid];

    // ---- stage this wave's spike sequence (128 ints, stride X*Y) ----
    {
        const int base = (b * TT) * (XDIM * YDIM) + x * YDIM + y;
        s_spk[wave][lane]      = spikes[base + lane * (XDIM * YDIM)];
        s_spk[wave][lane + 64] = spikes[base + (lane + 64) * (XDIM * YDIM)];
    }
    __syncthreads();

    const float fo   = fo_ptr[0];
    const float fo_h = fo * (1.0f / (float)H_DIM);
    const float fo1  = 1.0f + fo;

    float h = h_init[lane];

    // prefetch step 0's weight row
    int   sp = s_spk[wave][0];
    float w  = weights[sp * H_DIM + lane];

    #pragma unroll 2
    for (int t = 0; t < TT; ++t) {
        // prefetch next step's weight row (wraps at t=127; harmless reload)
        const int   sp_next = s_spk[wave][(t + 1) & (TT - 1)];
        const float w_next  = weights[sp_next * H_DIM + lane];

        const float eps = s_eps[sp][wave] * s_et[t];
        const float ht  = h * w;

        // 64-lane butterfly sum
        float s = ht;
        s += __shfl_xor(s, 1);
        s += __shfl_xor(s, 2);
        s += __shfl_xor(s, 4);
        s += __shfl_xor(s, 8);
        s += __shfl_xor(s, 16);
        s += __shfl_xor(s, 32);

        // fast reciprocals + one Newton step (~0.5 ulp)
        float rs = __builtin_amdgcn_rcpf(s);
        rs = rs * (2.0f - s * rs);
        const float denom = 1.0f + eps * fo1;
        float rd = __builtin_amdgcn_rcpf(denom);
        rd = rd * (2.0f - denom * rd);

        const float upd = (h + (eps * rs) * ht + eps * fo_h) * rd;
        h = (s > 1e-10f) ? upd : h;

        sp = sp_next;
        w  = w_next;
    }

    // ---- coalesce-ish output: out[b, h, x, y] ----
    s_out[wave][lane] = h;
    __syncthreads();
    {
        const int hh = tid >> 2;      // 64 h
        const int yy = tid & 3;       // 4 y
        out[b * (H_DIM * XDIM * YDIM) + hh * (XDIM * YDIM) + x * YDIM + y0 + yy]
            = s_out[yy][hh];
    }
}

extern "C" void kernel_launch(void* const* d_in, const int* in_sizes, int n_in,
                              void* d_out, int out_size, void* d_ws, size_t ws_size,
                              hipStream_t stream) {
    // inputs (setup_inputs order):
    // 0: input        [B,IN,X,Y] f32  (unused in forward)
    // 1: spikes       [B,T,X,Y]  i32
    // 2: epsilon_xy   [IN,X,Y]   f32
    // 3: epsilon_t_0  [T]        f32
    // 4: weights      [IN,H]     f32
    // 5: h_initial    [H]        f32
    // 6: forgetting_offset [1]   f32
    const int*   spikes  = (const int*)  d_in[1];
    const float* eps_xy  = (const float*)d_in[2];
    const float* eps_t   = (const float*)d_in[3];
    const float* weights = (const float*)d_in[4];
    const float* h_init  = (const float*)d_in[5];
    const float* fo_ptr  = (const float*)d_in[6];
    float*       out     = (float*)d_out;

    const int grid = BB * XDIM * (YDIM / 4);   // 1024
    sbs_scan_kernel<<<grid, 256, 0, stream>>>(
        spikes, eps_xy, eps_t, weights, h_init, fo_ptr, out);
}

// Round 2
// 94.992 us; speedup vs baseline: 1.1850x; 1.1850x over previous
//
#include <hip/hip_runtime.h>

// SbS hidden dynamics: per-pixel serial scan over T spikes.
#define BB      16
#define TT      128
#define XDIM    16
#define YDIM    16
#define IN_DIM  256
#define H_DIM   64

// Mapping: 1 wave (64 lanes) per pixel, lane = h index.
// Block = 256 threads = 4 waves = 4 pixels (b, x, y0..y0+3).
// Grid = 16*16*4 = 1024 blocks -> 4 blocks/CU, 16 waves/CU.
//
// Round-2 changes vs round-1:
//  - 64-lane sum via DPP row_shr/row_bcast adds + readlane (VALU-only),
//    replacing __shfl_xor butterfly (6 serial LDS-pipe round trips ~700cyc).
//  - all per-step scalars that depend only on (spike index, t) precomputed
//    in a 2-iteration prologue into LDS float4 P = (rd, eps*rd, eps*fo/H*rd):
//      h' = h*rd + (eps*rd)*(1/s)*h*w + eps*fo/H*rd  = fma(P.y*rs, ht, fma(h,P.x,P.z))
//  - weights row prefetched 2 steps ahead through a readfirstlane'd scalar base.

#define DPP_ADD(v, ctrl, rmask)                                                \
    v += __int_as_float(__builtin_amdgcn_update_dpp(                           \
        0, __float_as_int(v), (ctrl), (rmask), 0xf, true))

__device__ __forceinline__ float wave_sum64(float v) {
    DPP_ADD(v, 0x111, 0xf);  // row_shr:1
    DPP_ADD(v, 0x112, 0xf);  // row_shr:2
    DPP_ADD(v, 0x114, 0xf);  // row_shr:4
    DPP_ADD(v, 0x118, 0xf);  // row_shr:8  -> lanes 15/31/47/63 hold row sums
    DPP_ADD(v, 0x142, 0xa);  // row_bcast:15 -> rows 1,3: lane31=sum(0..31), lane63=sum(32..63)
    DPP_ADD(v, 0x143, 0xc);  // row_bcast:31 -> rows 2,3: lane63=sum(0..63)
    return __int_as_float(
        __builtin_amdgcn_readlane(__float_as_int(v), 63));  // uniform broadcast
}

__global__ __launch_bounds__(256) void sbs_scan_kernel(
    const int*   __restrict__ spikes,   // [B,T,X,Y]
    const float* __restrict__ eps_xy,   // [IN,X,Y]
    const float* __restrict__ eps_t,    // [T]
    const float* __restrict__ weights,  // [IN,H]
    const float* __restrict__ h_init,   // [H]
    const float* __restrict__ fo_ptr,   // [1]
    float*       __restrict__ out)      // [B,H,X,Y]
{
    __shared__ int    s_spk[4][TT];          // per-wave spike seq      2 KB
    __shared__ float4 s_P[4][TT];            // per-step scalar triple  8 KB
    __shared__ float  s_out[4][H_DIM + 1];   // output transpose        ~1 KB

    const int tid  = threadIdx.x;
    const int wave = tid >> 6;
    const int lane = tid & 63;

    const int bi = blockIdx.x;
    const int b  = bi >> 6;          // 16 b
    const int x  = (bi >> 2) & 15;   // 16 x
    const int y0 = (bi & 3) << 2;    // 4 y-groups
    const int y  = y0 + wave;

    // ---- stage this wave's spike sequence (wave-local: no barrier needed) ----
    {
        const int base = (b * TT) * (XDIM * YDIM) + x * YDIM + y;
        s_spk[wave][lane]      = spikes[base + lane * (XDIM * YDIM)];
        s_spk[wave][lane + 64] = spikes[base + (lane + 64) * (XDIM * YDIM)];
    }

    const float fo   = fo_ptr[0];
    const float fo_h = fo * (1.0f / (float)H_DIM);
    const float fo1  = 1.0f + fo;

    // ---- prologue: precompute per-step scalars (128 steps over 64 lanes) ----
    #pragma unroll
    for (int k = 0; k < 2; ++k) {
        const int   t   = lane + 64 * k;
        const int   sp  = s_spk[wave][t];
        const float exy = eps_xy[sp * (XDIM * YDIM) + x * YDIM + y];
        const float eps = exy * eps_t[t];
        const float den = 1.0f + eps * fo1;
        float rd = __builtin_amdgcn_rcpf(den);
        rd = rd * (2.0f - den * rd);                 // Newton step
        s_P[wave][t] = make_float4(rd, eps * rd, (eps * fo_h) * rd, 0.0f);
    }

    float h = h_init[lane];

    // ---- software pipeline: w 2 ahead, P 1 ahead ----
    const int sp0 = s_spk[wave][0];
    const int sp1 = s_spk[wave][1];
    float w  = (weights + __builtin_amdgcn_readfirstlane(sp0) * H_DIM)[lane];
    float w1 = (weights + __builtin_amdgcn_readfirstlane(sp1) * H_DIM)[lane];
    float4 P = s_P[wave][0];

    #pragma unroll 4
    for (int t = 0; t < TT; ++t) {
        // prefetch weights for t+2 (wraps harmlessly at the tail)
        const int sp2 = s_spk[wave][(t + 2) & (TT - 1)];
        const float w2 =
            (weights + __builtin_amdgcn_readfirstlane(sp2) * H_DIM)[lane];
        // prefetch P for t+1 (uniform LDS read -> broadcast)
        const float4 Pn = s_P[wave][(t + 1) & (TT - 1)];

        const float t3 = fmaf(h, P.x, P.z);   // off the reduce chain
        const float ht = h * w;
        const float s  = wave_sum64(ht);      // 6 DPP adds + readlane
        float rs = __builtin_amdgcn_rcpf(s);
        rs = rs * (2.0f - s * rs);            // Newton step
        const float upd = fmaf(P.y * rs, ht, t3);
        h = (s > 1e-10f) ? upd : h;           // s<=thr: keep h (upd may be NaN, discarded)

        w = w1; w1 = w2; P = Pn;
    }

    // ---- output transpose: out[b, h, x, y] ----
    s_out[wave][lane] = h;
    __syncthreads();
    {
        const int hh = tid >> 2;      // 64 h
        const int yy = tid & 3;       // 4 y
        out[b * (H_DIM * XDIM * YDIM) + hh * (XDIM * YDIM) + x * YDIM + y0 + yy]
            = s_out[yy][hh];
    }
}

extern "C" void kernel_launch(void* const* d_in, const int* in_sizes, int n_in,
                              void* d_out, int out_size, void* d_ws, size_t ws_size,
                              hipStream_t stream) {
    // inputs (setup_inputs order):
    // 0: input [B,IN,X,Y] f32 (unused)   1: spikes [B,T,X,Y] i32
    // 2: epsilon_xy [IN,X,Y] f32         3: epsilon_t_0 [T] f32
    // 4: weights [IN,H] f32              5: h_initial [H] f32
    // 6: forgetting_offset [1] f32
    const int*   spikes  = (const int*)  d_in[1];
    const float* eps_xy  = (const float*)d_in[2];
    const float* eps_t   = (const float*)d_in[3];
    const float* weights = (const float*)d_in[4];
    const float* h_init  = (const float*)d_in[5];
    const float* fo_ptr  = (const float*)d_in[6];
    float*       out     = (float*)d_out;

    const int grid = BB * XDIM * (YDIM / 4);   // 1024
    sbs_scan_kernel<<<grid, 256, 0, stream>>>(
        spikes, eps_xy, eps_t, weights, h_init, fo_ptr, out);
}

// Round 10
// 82.246 us; speedup vs baseline: 1.3686x; 1.1550x over previous
//
#include <hip/hip_runtime.h>

// SbS hidden dynamics: per-pixel serial scan over T spikes.
#define BB      16
#define TT      128
#define XDIM    16
#define YDIM    16
#define IN_DIM  256
#define H_DIM   64
#define XY      (XDIM*YDIM)

// Round-10: eliminate the thrice-failed v_permlane32_swap inline asm (rounds
// 3/4/9: 1.59e-3 / 1.46e-3 / 8.67e-3 — no swap-semantics hypothesis explains
// all three; suspected unmodeled permlane hazard in inline asm -> stale reads).
// New layout needs NO cross-row ops at all:
//   4 pixels per wave, one per 16-lane DPP row; lane holds 4 h-elems (float4).
//   64-elem pixel sum = within-row only: quad_perm xor1 (0xB1), xor2 (0x4E),
//   row_ror:4 (0x124), row_ror:8 (0x128). After quad sums, value is
//   quad-periodic, so ror:4 adds a neighbor quad and ror:8 the complementary
//   pair -> full sum in ALL 16 lanes, correct under either rotation direction.
//   Encodings: quad_perm bytes are canonical; row_ror shares the control table
//   with row_shr (0x111..0x118) verified on HW in round 2.
// Math identical to the PASSING round-2 kernel (NR on both reciprocals).
// P=(rd, eps*rd) precomputed in LDS; register queues: spk@t+5, w@t+3, P@t+2.
// Block 256 = 4 waves = 16 pixels = one (b,x) column; grid 256 = 1 block/CU.

#define DPP_ADD(v, ctrl)                                                      \
    v += __int_as_float(__builtin_amdgcn_update_dpp(                          \
        0, __float_as_int(v), (ctrl), 0xf, 0xf, true))

__global__ __launch_bounds__(256) void sbs_scan_kernel(
    const int*   __restrict__ spikes,   // [B,T,X,Y]
    const float* __restrict__ eps_xy,   // [IN,X,Y]
    const float* __restrict__ eps_t,    // [T]
    const float* __restrict__ weights,  // [IN,H]
    const float* __restrict__ h_init,   // [H]
    const float* __restrict__ fo_ptr,   // [1]
    float*       __restrict__ out)      // [B,H,X,Y]
{
    __shared__ int    s_spk[YDIM][TT];     //  8 KB spike seq per pixel
    __shared__ float2 s_P[YDIM][TT];       // 16 KB (rd, eps*rd) per step
    __shared__ float  s_out[YDIM][H_DIM];  //  4 KB output transpose

    const int tid = threadIdx.x;
    const int bi  = blockIdx.x;      // 256 blocks
    const int b   = bi >> 4;         // 16
    const int x   = bi & 15;         // 16  (block covers all 16 y)

    // ---- stage spikes: 2048 ints, 8 per thread (kept in regs for P pass) ----
    int spv[8];
    #pragma unroll
    for (int k = 0; k < 8; ++k) {
        const int idx = tid + k * 256;      // t = idx>>4, y = idx&15
        const int t = idx >> 4, yy = idx & 15;
        const int sp = spikes[(b * TT + t) * XY + x * YDIM + yy];
        spv[k] = sp;
        s_spk[yy][t] = sp;
    }

    const float fo   = fo_ptr[0];
    const float fo1  = 1.0f + fo;
    const float fo_h = fo * (1.0f / (float)H_DIM);

    // ---- per-step scalars: rd = 1/(1+eps(1+fo)) (NR), erd = eps*rd ----
    #pragma unroll
    for (int k = 0; k < 8; ++k) {
        const int idx = tid + k * 256;
        const int t = idx >> 4, yy = idx & 15;
        const float eps = eps_xy[spv[k] * XY + x * YDIM + yy] * eps_t[t];
        const float den = fmaf(eps, fo1, 1.0f);
        float rd = __builtin_amdgcn_rcpf(den);
        rd = fmaf(rd, fmaf(-den, rd, 1.0f), rd);
        s_P[yy][t] = make_float2(rd, eps * rd);
    }
    __syncthreads();

    // ---- per-lane geometry: row = pixel, 4 h-elems per lane ----
    const int wave = tid >> 6;
    const int lane = tid & 63;
    const int row  = lane >> 4;          // 0..3
    const int il   = lane & 15;          // 0..15
    const int y    = wave * 4 + row;     // pixel y

    const float4* __restrict__ w4 = (const float4*)weights;  // [IN][16]
    float4 h = ((const float4*)h_init)[il];                  // h[4il..4il+3]

    // ---- prefetch queues: spk@t+5, w@t+3, P@t+2 ----
    int    sq0 = s_spk[y][3];
    int    sq1 = s_spk[y][4];
    float4 wq0 = w4[s_spk[y][0] * 16 + il];
    float4 wq1 = w4[s_spk[y][1] * 16 + il];
    float4 wq2 = w4[s_spk[y][2] * 16 + il];
    float2 pq0 = s_P[y][0];
    float2 pq1 = s_P[y][1];

    #pragma unroll 4
    for (int t = 0; t < TT; ++t) {
        // prefetches (wrap at tail: valid data, results unused)
        const int    sq_n = s_spk[y][(t + 5) & (TT - 1)];
        const float4 wq_n = w4[sq0 * 16 + il];               // for step t+3
        const float2 pq_n = s_P[y][(t + 2) & (TT - 1)];

        // ---- step t ----
        const float ht0 = h.x * wq0.x;
        const float ht1 = h.y * wq0.y;
        const float ht2 = h.z * wq0.z;
        const float ht3 = h.w * wq0.w;
        float r = (ht0 + ht1) + (ht2 + ht3);
        DPP_ADD(r, 0xB1);    // quad_perm [1,0,3,2]  (xor1)
        DPP_ADD(r, 0x4E);    // quad_perm [2,3,0,1]  (xor2) -> quad sums
        DPP_ADD(r, 0x124);   // row_ror:4  + neighbor quad
        DPP_ADD(r, 0x128);   // row_ror:8  + complementary pair -> full sum
        const float s = r;   // 64-elem pixel sum in all 16 lanes of the row

        float rs = __builtin_amdgcn_rcpf(s);
        rs = fmaf(rs, fmaf(-s, rs, 1.0f), rs);   // Newton on 1/s

        const float rd   = pq0.x;
        const float erd  = pq0.y;
        const float erdf = erd * fo_h;
        const float k2   = erd * rs;
        const float u0 = fmaf(k2, ht0, fmaf(h.x, rd, erdf));
        const float u1 = fmaf(k2, ht1, fmaf(h.y, rd, erdf));
        const float u2 = fmaf(k2, ht2, fmaf(h.z, rd, erdf));
        const float u3 = fmaf(k2, ht3, fmaf(h.w, rd, erdf));
        const bool ok = (s > 1e-10f);
        h.x = ok ? u0 : h.x;
        h.y = ok ? u1 : h.y;
        h.z = ok ? u2 : h.z;
        h.w = ok ? u3 : h.w;

        // rotate queues
        sq0 = sq1; sq1 = sq_n;
        wq0 = wq1; wq1 = wq2; wq2 = wq_n;
        pq0 = pq1; pq1 = pq_n;
    }

    // ---- output transpose: out[b, h, x, y] ----
    *(float4*)&s_out[y][4 * il] = h;
    __syncthreads();
    #pragma unroll
    for (int k = 0; k < 4; ++k) {
        const int idx = tid + k * 256;   // 1024 = 64 h * 16 y
        const int hh = idx >> 4, yy = idx & 15;
        out[b * (H_DIM * XY) + hh * XY + x * YDIM + yy] = s_out[yy][hh];
    }
}

extern "C" void kernel_launch(void* const* d_in, const int* in_sizes, int n_in,
                              void* d_out, int out_size, void* d_ws, size_t ws_size,
                              hipStream_t stream) {
    // inputs (setup_inputs order):
    // 0: input [B,IN,X,Y] f32 (unused)   1: spikes [B,T,X,Y] i32
    // 2: epsilon_xy [IN,X,Y] f32         3: epsilon_t_0 [T] f32
    // 4: weights [IN,H] f32              5: h_initial [H] f32
    // 6: forgetting_offset [1] f32
    const int*   spikes  = (const int*)  d_in[1];
    const float* eps_xy  = (const float*)d_in[2];
    const float* eps_t   = (const float*)d_in[3];
    const float* weights = (const float*)d_in[4];
    const float* h_init  = (const float*)d_in[5];
    const float* fo_ptr  = (const float*)d_in[6];
    float*       out     = (float*)d_out;

    const int grid = BB * XDIM;   // 256 blocks, 16 pixels each
    sbs_scan_kernel<<<grid, 256, 0, stream>>>(
        spikes, eps_xy, eps_t, weights, h_init, fo_ptr, out);
}

// Round 11
// 80.566 us; speedup vs baseline: 1.3972x; 1.0208x over previous
//
#include <hip/hip_runtime.h>

// SbS hidden dynamics: per-pixel serial scan over T spikes.
#define BB      16
#define TT      128
#define XDIM    16
#define YDIM    16
#define IN_DIM  256
#define H_DIM   64
#define XY      (XDIM*YDIM)

// Round-11 = round-10 (PASSED, absmax 1.22e-4) + chain/stall shaving:
//  - removed s>1e-10 guard: Sum(h)==1 invariant + weights>1e-3 => s>=1e-3
//    always; the where-branch is dead in ref and kernel. (-cmp, -4 cndmask)
//  - dropped Newton on rs: rcp rel-err <=1e-5, damped by eps~0.05,h~0.015 ->
//    <=1e-6 accumulated over T=128 (round-3's 1.4e-3 was delta=0.18 from the
//    permlane bug, same scaling law). (-2 chain FMAs)
//  - eht_i = erd*ht_i precomputed during DPP shadow: post-rcp chain is a
//    single fma per element.
//  - deeper queues: w@t+4 (covers ~200cyc L2), spk@t+6, P@t+3.
//  - +1 padding on s_spk/s_P/s_out rows (unpadded strides put all rows of a
//    wave in the same bank / bank-pair).
// Layout (round-10, verified): 4 pixels/wave, one per 16-lane DPP row, 4
// h-elems per lane (float4). Reduce: quad_perm xor1(0xB1), xor2(0x4E),
// row_ror:4(0x124), row_ror:8(0x128) -> full 64-elem sum in all 16 lanes,
// no cross-row ops, no inline asm. 256 blocks = 1/CU, 1024 waves = 1/SIMD.

#define DPP_ADD(v, ctrl)                                                      \
    v += __int_as_float(__builtin_amdgcn_update_dpp(                          \
        0, __float_as_int(v), (ctrl), 0xf, 0xf, true))

__global__ __launch_bounds__(256) void sbs_scan_kernel(
    const int*   __restrict__ spikes,   // [B,T,X,Y]
    const float* __restrict__ eps_xy,   // [IN,X,Y]
    const float* __restrict__ eps_t,    // [T]
    const float* __restrict__ weights,  // [IN,H]
    const float* __restrict__ h_init,   // [H]
    const float* __restrict__ fo_ptr,   // [1]
    float*       __restrict__ out)      // [B,H,X,Y]
{
    __shared__ int    s_spk[YDIM][TT + 1];     // +1 pad: rows hit distinct banks
    __shared__ float2 s_P[YDIM][TT + 1];       // +1 pad
    __shared__ float  s_out[YDIM][H_DIM + 1];  // +1 pad (epilogue col reads)

    const int tid = threadIdx.x;
    const int bi  = blockIdx.x;      // 256 blocks
    const int b   = bi >> 4;         // 16
    const int x   = bi & 15;         // 16  (block covers all 16 y)

    // ---- stage spikes: 2048 ints, 8 per thread (kept in regs for P pass) ----
    int spv[8];
    #pragma unroll
    for (int k = 0; k < 8; ++k) {
        const int idx = tid + k * 256;      // t = idx>>4, y = idx&15
        const int t = idx >> 4, yy = idx & 15;
        const int sp = spikes[(b * TT + t) * XY + x * YDIM + yy];
        spv[k] = sp;
        s_spk[yy][t] = sp;
    }

    const float fo   = fo_ptr[0];
    const float fo1  = 1.0f + fo;
    const float fo_h = fo * (1.0f / (float)H_DIM);

    // ---- per-step scalars: rd = 1/(1+eps(1+fo)) (NR, off-chain), erd ----
    #pragma unroll
    for (int k = 0; k < 8; ++k) {
        const int idx = tid + k * 256;
        const int t = idx >> 4, yy = idx & 15;
        const float eps = eps_xy[spv[k] * XY + x * YDIM + yy] * eps_t[t];
        const float den = fmaf(eps, fo1, 1.0f);
        float rd = __builtin_amdgcn_rcpf(den);
        rd = fmaf(rd, fmaf(-den, rd, 1.0f), rd);
        s_P[yy][t] = make_float2(rd, eps * rd);
    }
    __syncthreads();

    // ---- per-lane geometry: row = pixel, 4 h-elems per lane ----
    const int wave = tid >> 6;
    const int lane = tid & 63;
    const int row  = lane >> 4;          // 0..3
    const int il   = lane & 15;          // 0..15
    const int y    = wave * 4 + row;     // pixel y

    const float4* __restrict__ w4 = (const float4*)weights;  // [IN][16]
    float4 h = ((const float4*)h_init)[il];                  // h[4il..4il+3]

    // ---- prefetch queues: spk@t+6, w@t+4, P@t+3 ----
    int    sq0 = s_spk[y][4];
    int    sq1 = s_spk[y][5];
    float4 wq0 = w4[s_spk[y][0] * 16 + il];
    float4 wq1 = w4[s_spk[y][1] * 16 + il];
    float4 wq2 = w4[s_spk[y][2] * 16 + il];
    float4 wq3 = w4[s_spk[y][3] * 16 + il];
    float2 pq0 = s_P[y][0];
    float2 pq1 = s_P[y][1];
    float2 pq2 = s_P[y][2];

    #pragma unroll 4
    for (int t = 0; t < TT; ++t) {
        // prefetches (wrap at tail: valid rows, results unused)
        const int    sq_n = s_spk[y][(t + 6) & (TT - 1)];
        const float4 wq_n = w4[sq0 * 16 + il];               // for step t+4
        const float2 pq_n = s_P[y][(t + 3) & (TT - 1)];

        // ---- step t ----
        const float ht0 = h.x * wq0.x;
        const float ht1 = h.y * wq0.y;
        const float ht2 = h.z * wq0.z;
        const float ht3 = h.w * wq0.w;
        float r = (ht0 + ht1) + (ht2 + ht3);

        // shadow work (independent of the reduce; fills DPP latency)
        const float rd   = pq0.x;
        const float erd  = pq0.y;
        const float erdf = erd * fo_h;
        const float eht0 = erd * ht0;
        const float eht1 = erd * ht1;
        const float eht2 = erd * ht2;
        const float eht3 = erd * ht3;
        const float t30 = fmaf(h.x, rd, erdf);
        const float t31 = fmaf(h.y, rd, erdf);
        const float t32 = fmaf(h.z, rd, erdf);
        const float t33 = fmaf(h.w, rd, erdf);

        DPP_ADD(r, 0xB1);    // quad_perm [1,0,3,2]  (xor1)
        DPP_ADD(r, 0x4E);    // quad_perm [2,3,0,1]  (xor2) -> quad sums
        DPP_ADD(r, 0x124);   // row_ror:4  + neighbor quad
        DPP_ADD(r, 0x128);   // row_ror:8  + complementary pair -> full sum

        const float rs = __builtin_amdgcn_rcpf(r);  // s>=1e-3 structurally
        h.x = fmaf(rs, eht0, t30);
        h.y = fmaf(rs, eht1, t31);
        h.z = fmaf(rs, eht2, t32);
        h.w = fmaf(rs, eht3, t33);

        // rotate queues
        sq0 = sq1; sq1 = sq_n;
        wq0 = wq1; wq1 = wq2; wq2 = wq3; wq3 = wq_n;
        pq0 = pq1; pq1 = pq2; pq2 = pq_n;
    }

    // ---- output transpose: out[b, h, x, y] ----
    *(float4*)&s_out[y][4 * il] = h;
    __syncthreads();
    #pragma unroll
    for (int k = 0; k < 4; ++k) {
        const int idx = tid + k * 256;   // 1024 = 64 h * 16 y
        const int hh = idx >> 4, yy = idx & 15;
        out[b * (H_DIM * XY) + hh * XY + x * YDIM + yy] = s_out[yy][hh];
    }
}

extern "C" void kernel_launch(void* const* d_in, const int* in_sizes, int n_in,
                              void* d_out, int out_size, void* d_ws, size_t ws_size,
                              hipStream_t stream) {
    // inputs (setup_inputs order):
    // 0: input [B,IN,X,Y] f32 (unused)   1: spikes [B,T,X,Y] i32
    // 2: epsilon_xy [IN,X,Y] f32         3: epsilon_t_0 [T] f32
    // 4: weights [IN,H] f32              5: h_initial [H] f32
    // 6: forgetting_offset [1] f32
    const int*   spikes  = (const int*)  d_in[1];
    const float* eps_xy  = (const float*)d_in[2];
    const float* eps_t   = (const float*)d_in[3];
    const float* weights = (const float*)d_in[4];
    const float* h_init  = (const float*)d_in[5];
    const float* fo_ptr  = (const float*)d_in[6];
    float*       out     = (float*)d_out;

    const int grid = BB * XDIM;   // 256 blocks, 16 pixels each
    sbs_scan_kernel<<<grid, 256, 0, stream>>>(
        spikes, eps_xy, eps_t, weights, h_init, fo_ptr, out);
}

// Round 12
// 76.962 us; speedup vs baseline: 1.4626x; 1.0468x over previous
//
#include <hip/hip_runtime.h>

// SbS hidden dynamics: per-pixel serial scan over T spikes.
#define BB      16
#define TT      128
#define XDIM    16
#define YDIM    16
#define IN_DIM  256
#define H_DIM   64
#define XY      (XDIM*YDIM)

// Round-12 = round-11 math (validated: no guard, raw rcp on s) + LDS traffic
// batched to group-of-4-steps granularity. Diagnosis: R11 kernel ~19.8us =
// ~370cyc/step while the VALU chain models at ~60-70cyc; the residue matches
// per-step LDS round trips (2/step) exposed at 1 wave/SIMD with conservative
// lgkmcnt drains (~120cyc single-outstanding LDS, m117). Changes:
//  - spikes packed int4: 1 ds_read_b128 per 4 steps, double-buffered 2 groups
//    ahead (8-step issue->use distance).
//  - P packed float4 (2 steps each): 2 ds_read_b128 per 4 steps, 2 groups ahead.
//  - 4 weight-row global prefetches issued together at group start for group
//    g+1 (4-8 step distance covers L1-miss->L2 latency of the 64KB table).
// Layout (validated R10/R11): 4 pixels/wave, one per 16-lane DPP row, float4
// h per lane. Reduce: quad_perm 0xB1, 0x4E + row_ror 0x124, 0x128 -> full
// 64-elem sum in all 16 row lanes; no cross-row ops, no inline asm.
// 256 blocks = 1/CU, 1024 waves = 1/SIMD.

#define DPP_ADD(v, ctrl)                                                      \
    v += __int_as_float(__builtin_amdgcn_update_dpp(                          \
        0, __float_as_int(v), (ctrl), 0xf, 0xf, true))

// one scan step; reads/writes h (float4), uses W (float4), RD/ERD scalars
#define STEP(W, RD, ERD)                                                      \
    {                                                                         \
        const float ht0 = h.x * (W).x;                                        \
        const float ht1 = h.y * (W).y;                                        \
        const float ht2 = h.z * (W).z;                                        \
        const float ht3 = h.w * (W).w;                                        \
        float r = (ht0 + ht1) + (ht2 + ht3);                                  \
        const float erdf = (ERD) * fo_h;                                      \
        const float eht0 = (ERD) * ht0;                                       \
        const float eht1 = (ERD) * ht1;                                       \
        const float eht2 = (ERD) * ht2;                                       \
        const float eht3 = (ERD) * ht3;                                       \
        const float t30 = fmaf(h.x, (RD), erdf);                              \
        const float t31 = fmaf(h.y, (RD), erdf);                              \
        const float t32 = fmaf(h.z, (RD), erdf);                              \
        const float t33 = fmaf(h.w, (RD), erdf);                              \
        DPP_ADD(r, 0xB1);   /* quad_perm xor1 */                              \
        DPP_ADD(r, 0x4E);   /* quad_perm xor2 -> quad sums */                 \
        DPP_ADD(r, 0x124);  /* row_ror:4 */                                   \
        DPP_ADD(r, 0x128);  /* row_ror:8 -> full 64-elem sum */               \
        const float rs = __builtin_amdgcn_rcpf(r); /* s>=1e-3 structurally */ \
        h.x = fmaf(rs, eht0, t30);                                            \
        h.y = fmaf(rs, eht1, t31);                                            \
        h.z = fmaf(rs, eht2, t32);                                            \
        h.w = fmaf(rs, eht3, t33);                                            \
    }

__global__ __launch_bounds__(256) void sbs_scan_kernel(
    const int*   __restrict__ spikes,   // [B,T,X,Y]
    const float* __restrict__ eps_xy,   // [IN,X,Y]
    const float* __restrict__ eps_t,    // [T]
    const float* __restrict__ weights,  // [IN,H]
    const float* __restrict__ h_init,   // [H]
    const float* __restrict__ fo_ptr,   // [1]
    float*       __restrict__ out)      // [B,H,X,Y]
{
    __shared__ int4   s_spk4[YDIM][TT / 4 + 1];   // spikes, 4 steps/entry
    __shared__ float4 s_P4[YDIM][TT / 2 + 1];     // (rd,erd)x2, 2 steps/entry
    __shared__ float  s_out[YDIM][H_DIM + 1];     // output transpose

    const int tid = threadIdx.x;
    const int bi  = blockIdx.x;      // 256 blocks
    const int b   = bi >> 4;         // 16
    const int x   = bi & 15;         // 16  (block covers all 16 y)

    // ---- stage spikes: 2048 ints, 8 per thread (kept in regs for P pass) ----
    int spv[8];
    #pragma unroll
    for (int k = 0; k < 8; ++k) {
        const int idx = tid + k * 256;      // t = idx>>4, y = idx&15
        const int t = idx >> 4, yy = idx & 15;
        const int sp = spikes[(b * TT + t) * XY + x * YDIM + yy];
        spv[k] = sp;
        ((int*)s_spk4[yy])[t] = sp;         // packed: entry t/4, comp t%4
    }

    const float fo   = fo_ptr[0];
    const float fo1  = 1.0f + fo;
    const float fo_h = fo * (1.0f / (float)H_DIM);

    // ---- per-step scalars: rd = 1/(1+eps(1+fo)) (NR, off-chain), erd ----
    #pragma unroll
    for (int k = 0; k < 8; ++k) {
        const int idx = tid + k * 256;
        const int t = idx >> 4, yy = idx & 15;
        const float eps = eps_xy[spv[k] * XY + x * YDIM + yy] * eps_t[t];
        const float den = fmaf(eps, fo1, 1.0f);
        float rd = __builtin_amdgcn_rcpf(den);
        rd = fmaf(rd, fmaf(-den, rd, 1.0f), rd);
        ((float2*)s_P4[yy])[t] = make_float2(rd, eps * rd);  // entry t/2
    }
    __syncthreads();

    // ---- per-lane geometry: row = pixel, 4 h-elems per lane ----
    const int wave = tid >> 6;
    const int lane = tid & 63;
    const int row  = lane >> 4;          // 0..3
    const int il   = lane & 15;          // 0..15
    const int y    = wave * 4 + row;     // pixel y

    const float4* __restrict__ w4 = (const float4*)weights;  // [IN][16]
    const int4*   __restrict__ Sy = s_spk4[y];
    const float4* __restrict__ Py = s_P4[y];

    float4 h = ((const float4*)h_init)[il];

    // ---- queues (group = 4 steps; 32 groups) ----
    // weights for group 0 loaded directly; sA = spikes(group1) feeds the
    // group-1 weight prefetch issued during group 0; sB = spikes(group2).
    const int4 s0 = Sy[0];
    int4   sA  = Sy[1];
    int4   sB  = Sy[2];
    float4 wq0 = w4[s0.x * 16 + il];
    float4 wq1 = w4[s0.y * 16 + il];
    float4 wq2 = w4[s0.z * 16 + il];
    float4 wq3 = w4[s0.w * 16 + il];
    float4 PA0 = Py[0], PA1 = Py[1];     // group 0
    float4 PB0 = Py[2], PB1 = Py[3];     // group 1

    #pragma unroll 2
    for (int g = 0; g < TT / 4; ++g) {
        // group-level prefetches (issue->use distance: 8 steps)
        const int4   s_in  = Sy[(g + 3) & 31];
        const float4 p_in0 = Py[(2 * g + 4) & 63];
        const float4 p_in1 = Py[(2 * g + 5) & 63];
        // weight rows for group g+1 (distance 4-8 steps)
        const float4 wn0 = w4[sA.x * 16 + il];
        const float4 wn1 = w4[sA.y * 16 + il];
        const float4 wn2 = w4[sA.z * 16 + il];
        const float4 wn3 = w4[sA.w * 16 + il];

        STEP(wq0, PA0.x, PA0.y);
        STEP(wq1, PA0.z, PA0.w);
        STEP(wq2, PA1.x, PA1.y);
        STEP(wq3, PA1.z, PA1.w);

        wq0 = wn0; wq1 = wn1; wq2 = wn2; wq3 = wn3;
        PA0 = PB0; PA1 = PB1; PB0 = p_in0; PB1 = p_in1;
        sA = sB; sB = s_in;
    }

    // ---- output transpose: out[b, h, x, y] ----
    *(float4*)&s_out[y][4 * il] = h;
    __syncthreads();
    #pragma unroll
    for (int k = 0; k < 4; ++k) {
        const int idx = tid + k * 256;   // 1024 = 64 h * 16 y
        const int hh = idx >> 4, yy = idx & 15;
        out[b * (H_DIM * XY) + hh * XY + x * YDIM + yy] = s_out[yy][hh];
    }
}

extern "C" void kernel_launch(void* const* d_in, const int* in_sizes, int n_in,
                              void* d_out, int out_size, void* d_ws, size_t ws_size,
                              hipStream_t stream) {
    // inputs (setup_inputs order):
    // 0: input [B,IN,X,Y] f32 (unused)   1: spikes [B,T,X,Y] i32
    // 2: epsilon_xy [IN,X,Y] f32         3: epsilon_t_0 [T] f32
    // 4: weights [IN,H] f32              5: h_initial [H] f32
    // 6: forgetting_offset [1] f32
    const int*   spikes  = (const int*)  d_in[1];
    const float* eps_xy  = (const float*)d_in[2];
    const float* eps_t   = (const float*)d_in[3];
    const float* weights = (const float*)d_in[4];
    const float* h_init  = (const float*)d_in[5];
    const float* fo_ptr  = (const float*)d_in[6];
    float*       out     = (float*)d_out;

    const int grid = BB * XDIM;   // 256 blocks, 16 pixels each
    sbs_scan_kernel<<<grid, 256, 0, stream>>>(
        spikes, eps_xy, eps_t, weights, h_init, fo_ptr, out);
}